// Round 8
// baseline (146.157 us; speedup 1.0000x reference)
//
#include <hip/hip_runtime.h>
#include <hip/hip_bf16.h>

#define BATCH 64
#define UNITS 1024
#define CHUNK 8192
#define JB 32          // chunks per scan block
#define NSPLIT 4       // WGs per column in gather

typedef unsigned int u32;
typedef unsigned short u16;

// ---------------- zero a uint4-aligned region ------------------------------
__global__ __launch_bounds__(256)
void zero4_kernel(uint4* __restrict__ p, int n4) {
    int i = blockIdx.x * 256 + threadIdx.x;
    const int stride = gridDim.x * 256;
    const uint4 z = make_uint4(0u, 0u, 0u, 0u);
    for (; i < n4; i += stride) p[i] = z;
}

// ---------------- fused: transpose x -> bf16 xT  AND  per-chunk histogram --
__global__ __launch_bounds__(256)
void prep_kernel(const float* __restrict__ x, u16* __restrict__ xT,
                 const int* __restrict__ col, u32* __restrict__ hist2,
                 int nfeat, int nT, int nnz) {
    __shared__ float tile[64][65];
    __shared__ u32 lh[UNITS];
    const int bid = blockIdx.x;
    const int tid = threadIdx.x;
    if (bid < nT) {
        const int c0 = bid * 64;
        const int tx = tid & 63, ty = tid >> 6;
        for (int b = ty; b < 64; b += 4) {
            int c = c0 + tx;
            if (c < nfeat) tile[b][tx] = x[(size_t)b * nfeat + c];   // coalesced
        }
        __syncthreads();
        for (int i = ty; i < 64; i += 4) {
            int c = c0 + i;
            if (c < nfeat) {
                __hip_bfloat16 h = __float2bfloat16(tile[tx][i]);
                xT[(size_t)c * 64 + tx] = *(u16*)&h;                 // coalesced
            }
        }
    } else {
        const int g = bid - nT;
        for (int i = tid; i < UNITS; i += 256) lh[i] = 0u;
        __syncthreads();
        const int g0 = g * CHUNK;
        const int n = min(CHUNK, nnz - g0);
        for (int i = tid; i < n; i += 256)
            atomicAdd(&lh[col[g0 + i]], 1u);
        __syncthreads();
        for (int c = tid; c < UNITS; c += 256)
            hist2[(size_t)g * UNITS + c] = lh[c];
    }
}

// ---------------- scanA: per-block-of-JB-chunks column partials ------------
__global__ __launch_bounds__(1024)
void scanA_kernel(const u32* __restrict__ hist2, u32* __restrict__ partial,
                  int nchunk) {
    const int j = blockIdx.x, c = threadIdx.x;
    const int gs = j * JB, ge = min(gs + JB, nchunk);
    u32 s = 0;
#pragma unroll 8
    for (int g = gs; g < ge; ++g) s += hist2[(size_t)g * UNITS + c];  // coalesced
    partial[(size_t)j * UNITS + c] = s;
}

// ---------------- scanB: column exclusive scan + per-block bases -----------
__global__ __launch_bounds__(1024)
void scanB_kernel(const u32* __restrict__ partial, u32* __restrict__ jb,
                  u32* __restrict__ col_start, int nblk) {
    const int c = threadIdx.x;
    u32 tot = 0;
    for (int j = 0; j < nblk; ++j) tot += partial[(size_t)j * UNITS + c];
    __shared__ u32 a[UNITS];
    a[c] = tot;
    __syncthreads();
    for (int off = 1; off < UNITS; off <<= 1) {
        u32 add = (c >= off) ? a[c - off] : 0u;
        u32 v = a[c];
        __syncthreads();
        a[c] = v + add;
        __syncthreads();
    }
    u32 run = a[c] - tot;                    // exclusive column prefix
    col_start[c] = run;
    if (c == UNITS - 1) col_start[UNITS] = a[UNITS - 1];
    for (int j = 0; j < nblk; ++j) {
        jb[(size_t)j * UNITS + c] = run;
        run += partial[(size_t)j * UNITS + c];
    }
}

// ---------------- reorder: pack (bf16(w)<<16 | row) into column bins -------
// 8-entry batches: 8 independent load-chains -> 8 LDS atomics -> 8 stores
// (MLP; the round-7 version was an un-batched dependent chain).
__global__ __launch_bounds__(512)
void reorder_kernel(const int* __restrict__ row, const int* __restrict__ col,
                    const float* __restrict__ w, const u32* __restrict__ hist2,
                    const u32* __restrict__ jb, u32* __restrict__ sorted, int nnz) {
    __shared__ u32 cur[UNITS];
    const int tid = threadIdx.x;
    const int g = blockIdx.x;
    const int j = g / JB, gs = j * JB;
    for (int c = tid; c < UNITS; c += 512) {
        u32 v = jb[(size_t)j * UNITS + c];
#pragma unroll 4
        for (int gp = gs; gp < g; ++gp) v += hist2[(size_t)gp * UNITS + c];
        cur[c] = v;
    }
    __syncthreads();
    const int g0 = g * CHUNK;
    const int n = min(CHUNK, nnz - g0);
    if (n == CHUNK) {
        for (int j2 = 0; j2 < CHUNK / 512; j2 += 8) {     // 2 batches of 8
            u32 cc[8], pk[8], lo[8];
#pragma unroll
            for (int q = 0; q < 8; ++q) {
                const int k = g0 + tid + 512 * (j2 + q);
                cc[q] = (u32)col[k];
                __hip_bfloat16 h = __float2bfloat16(w[k]);
                pk[q] = ((u32)(*(const u16*)&h) << 16) | (u32)row[k];
            }
#pragma unroll
            for (int q = 0; q < 8; ++q) lo[q] = atomicAdd(&cur[cc[q]], 1u);
#pragma unroll
            for (int q = 0; q < 8; ++q) sorted[lo[q]] = pk[q];
        }
    } else {
        for (int i = tid; i < n; i += 512) {
            const int k = g0 + i;
            const u32 c = (u32)col[k];
            __hip_bfloat16 h = __float2bfloat16(w[k]);
            const u32 pk = ((u32)(*(const u16*)&h) << 16) | (u32)row[k];
            const u32 lo = atomicAdd(&cur[c], 1u);
            sorted[lo] = pk;
        }
    }
}

// ---------------- gather: NSPLIT WGs per column, 64 batches = 64 lanes -----
// Uniform-pointer addressing: readlane entry -> SGPR row base; the per-lane
// voffset (lane*2) is loop-invariant -> per entry ~2 VALU + 1 VMEM.
// Partial sums combined via unsafeAtomicAdd into pre-zeroed out.
__global__ __launch_bounds__(256)
void gather_kernel(const u16* __restrict__ xTu, const u32* __restrict__ sorted,
                   const u32* __restrict__ col_start, float* __restrict__ out) {
    const int u = blockIdx.x >> 2;          // column
    const int part = blockIdx.x & 3;        // NSPLIT=4
    const int tid = threadIdx.x;
    const int wv = tid >> 6, lane = tid & 63;   // lane = batch
    const u32 s = col_start[u], e = col_start[u + 1];
    float acc0 = 0.f, acc1 = 0.f, acc2 = 0.f, acc3 = 0.f;
    for (u32 b0 = s + (u32)(part * 4 + wv) * 64u; b0 < e; b0 += (u32)(NSPLIT * 4) * 64u) {
        u32 pk = 0u;                                 // pad: w=+0 -> no-op
        if (b0 + (u32)lane < e) pk = sorted[b0 + (u32)lane];
#pragma unroll
        for (int t = 0; t < 64; t += 4) {
            const u32 e0 = (u32)__builtin_amdgcn_readlane((int)pk, t);
            const u32 e1 = (u32)__builtin_amdgcn_readlane((int)pk, t + 1);
            const u32 e2 = (u32)__builtin_amdgcn_readlane((int)pk, t + 2);
            const u32 e3 = (u32)__builtin_amdgcn_readlane((int)pk, t + 3);
            const u16* p0 = xTu + ((e0 & 0xffffu) << 6);   // wave-uniform base
            const u16* p1 = xTu + ((e1 & 0xffffu) << 6);
            const u16* p2 = xTu + ((e2 & 0xffffu) << 6);
            const u16* p3 = xTu + ((e3 & 0xffffu) << 6);
            const float x0 = __uint_as_float(((u32)p0[lane]) << 16);
            const float x1 = __uint_as_float(((u32)p1[lane]) << 16);
            const float x2 = __uint_as_float(((u32)p2[lane]) << 16);
            const float x3 = __uint_as_float(((u32)p3[lane]) << 16);
            acc0 = fmaf(x0, __uint_as_float(e0 & 0xffff0000u), acc0);
            acc1 = fmaf(x1, __uint_as_float(e1 & 0xffff0000u), acc1);
            acc2 = fmaf(x2, __uint_as_float(e2 & 0xffff0000u), acc2);
            acc3 = fmaf(x3, __uint_as_float(e3 & 0xffff0000u), acc3);
        }
    }
    float tot = (acc0 + acc1) + (acc2 + acc3);
    __shared__ float red[4][64];
    red[wv][lane] = tot;
    __syncthreads();
    if (wv == 0)
        unsafeAtomicAdd(&out[(size_t)lane * UNITS + u],
                        red[0][lane] + red[1][lane] + red[2][lane] + red[3][lane]);
}

// ---------------- small-ws fallbacks ---------------------------------------
__global__ __launch_bounds__(1024, 1)
void scatter_fallback_kernel(const u16* __restrict__ xT, const float* __restrict__ w,
                             const int* __restrict__ row_idx, const int* __restrict__ col_idx,
                             float* __restrict__ out, int nnz) {
    extern __shared__ float priv[];
    const int tid = threadIdx.x;
    for (int i = tid; i < 32 * UNITS; i += 1024) priv[i] = 0.0f;
    __syncthreads();
    const int bid = blockIdx.x, half = bid >> 7, wgIdx = bid & 127;
    const int wave = tid >> 6, lane = tid & 63, h = lane >> 5, bl = lane & 31;
    const int per = (nnz + 127) >> 7;
    const int k0 = wgIdx * per, kend = min(k0 + per, nnz);
    const u16* xTh = xT + half * 32 + bl;
    for (int k = k0 + wave * 2 + h; k < kend; k += 32) {
        const int r = row_idx[k], c = col_idx[k];
        const float xv = __uint_as_float(((u32)xTh[(size_t)r * 64]) << 16);
        atomicAdd(&priv[c * 32 + bl], xv * w[k]);
    }
    __syncthreads();
    for (int i = tid; i < 32 * UNITS; i += 1024) {
        int c = i >> 5, b = half * 32 + (i & 31);
        unsafeAtomicAdd(&out[b * UNITS + c], priv[i]);
    }
}

__global__ __launch_bounds__(256)
void fallback_kernel(const float* __restrict__ x, const float* __restrict__ w,
                     const int* __restrict__ row_idx, const int* __restrict__ col_idx,
                     float* __restrict__ out, int nnz, int nfeat) {
    const int nwaves = (gridDim.x * blockDim.x) >> 6;
    const int wid = (blockIdx.x * blockDim.x + threadIdx.x) >> 6;
    const int lane = threadIdx.x & 63;
    for (int k = wid; k < nnz; k += nwaves) {
        const int r = row_idx[k], c = col_idx[k];
        unsafeAtomicAdd(&out[lane * UNITS + c], x[(size_t)lane * nfeat + r] * w[k]);
    }
}

static inline size_t align256(size_t v) { return (v + 255) & ~(size_t)255; }

extern "C" void kernel_launch(void* const* d_in, const int* in_sizes, int n_in,
                              void* d_out, int out_size, void* d_ws, size_t ws_size,
                              hipStream_t stream) {
    const float* x       = (const float*)d_in[0];
    const float* w       = (const float*)d_in[1];
    const int*   row_idx = (const int*)d_in[2];
    const int*   col_idx = (const int*)d_in[3];
    float*       out     = (float*)d_out;
    const int    nnz     = in_sizes[1];
    const int    nfeat   = in_sizes[0] / BATCH;
    const int    nchunk  = (nnz + CHUNK - 1) / CHUNK;
    const int    nblk    = (nchunk + JB - 1) / JB;
    const int    nT      = (nfeat + 63) / 64;

    // ws layout
    const size_t xT_bytes = (size_t)nfeat * 64 * sizeof(u16);                    // 6.4 MB
    size_t o = align256(xT_bytes);
    const size_t sorted_off = o;  o = align256(o + (size_t)nnz * sizeof(u32));   // 8 MB
    const size_t hist2_off  = o;  o = align256(o + (size_t)nchunk * UNITS * sizeof(u32));
    const size_t part_off   = o;  o = align256(o + (size_t)nblk * UNITS * sizeof(u32));
    const size_t jb_off     = o;  o = align256(o + (size_t)nblk * UNITS * sizeof(u32));
    const size_t cs_off     = o;  o = align256(o + (UNITS + 1) * sizeof(u32));

    const int nOut4 = (out_size * 4 + 15) / 16;

    if (ws_size >= o && nfeat <= 65536 && nblk <= 64) {
        u16* xT        = (u16*)d_ws;
        u32* sorted    = (u32*)((char*)d_ws + sorted_off);
        u32* hist2     = (u32*)((char*)d_ws + hist2_off);
        u32* partial   = (u32*)((char*)d_ws + part_off);
        u32* jb        = (u32*)((char*)d_ws + jb_off);
        u32* col_start = (u32*)((char*)d_ws + cs_off);

        zero4_kernel<<<64, 256, 0, stream>>>((uint4*)out, nOut4);
        prep_kernel<<<nT + nchunk, 256, 0, stream>>>(x, xT, col_idx, hist2,
                                                     nfeat, nT, nnz);
        scanA_kernel<<<nblk, 1024, 0, stream>>>(hist2, partial, nchunk);
        scanB_kernel<<<1, 1024, 0, stream>>>(partial, jb, col_start, nblk);
        reorder_kernel<<<nchunk, 512, 0, stream>>>(row_idx, col_idx, w, hist2,
                                                   jb, sorted, nnz);
        gather_kernel<<<UNITS * NSPLIT, 256, 0, stream>>>(xT, sorted, col_start, out);
    } else if (ws_size >= xT_bytes) {
        u16* xT = (u16*)d_ws;
        zero4_kernel<<<64, 256, 0, stream>>>((uint4*)out, nOut4);
        prep_kernel<<<nT, 256, 0, stream>>>(x, xT, col_idx, nullptr, nfeat, nT, 0);
        scatter_fallback_kernel<<<256, 1024, 32 * UNITS * sizeof(float), stream>>>(
            xT, w, row_idx, col_idx, out, nnz);
    } else {
        zero4_kernel<<<64, 256, 0, stream>>>((uint4*)out, nOut4);
        fallback_kernel<<<2048, 256, 0, stream>>>(x, w, row_idx, col_idx, out, nnz, nfeat);
    }
}